// Round 12
// baseline (263.771 us; speedup 1.0000x reference)
//
#include <hip/hip_runtime.h>
#include <hip/hip_fp16.h>
#include <math.h>

#define N_NODES 50000
#define N_EDGES 300000
#define E_TOT (N_EDGES + N_NODES)
#define IN_CH 128
#define HIDDEN 64
#define OUT_CH 40
#define NUM_LAYERS 4
#define NCHUNK ((N_NODES + 255) / 256)  // 196
#define NTILES (N_NODES / 16)           // 3125 (exact)
#define QKV_WPR 512                     // waves per role in k_qkv_mfma
// heads = 8, d_head = 8, scale = 1/sqrt(8)

typedef _Float16 h8 __attribute__((ext_vector_type(8)));
typedef float f32x4 __attribute__((ext_vector_type(4)));
typedef float f32x2 __attribute__((ext_vector_type(2)));

#define MFMA16(a, b, c) __builtin_amdgcn_mfma_f32_16x16x32_f16((a), (b), (c), 0, 0, 0)

__global__ void k_count_init(int* count, int* fill) {
    int n = blockIdx.x * blockDim.x + threadIdx.x;
    if (n < N_NODES) { count[n] = 1; fill[n] = 1; }  // slot 0 = self-loop
}

__global__ void k_count(const int* __restrict__ dst, int* count) {
    int e = blockIdx.x * blockDim.x + threadIdx.x;
    if (e < N_EDGES) atomicAdd(&count[dst[e]], 1);
}

__global__ __launch_bounds__(256) void k_scan_a(const int* __restrict__ count,
                                                int* __restrict__ loc,
                                                int* __restrict__ psum) {
    __shared__ int s[256];
    int tid = threadIdx.x;
    int g = blockIdx.x * 256 + tid;
    int v = (g < N_NODES) ? count[g] : 0;
    s[tid] = v;
    __syncthreads();
    for (int off = 1; off < 256; off <<= 1) {
        int t = (tid >= off) ? s[tid - off] : 0;
        __syncthreads();
        s[tid] += t;
        __syncthreads();
    }
    if (g < N_NODES) loc[g] = s[tid] - v;  // exclusive
    if (tid == 255) psum[blockIdx.x] = s[255];
}

__global__ __launch_bounds__(256) void k_scan_b(int* psum) {
    __shared__ int s[256];
    int tid = threadIdx.x;
    int v = (tid < NCHUNK) ? psum[tid] : 0;
    s[tid] = v;
    __syncthreads();
    for (int off = 1; off < 256; off <<= 1) {
        int t = (tid >= off) ? s[tid - off] : 0;
        __syncthreads();
        s[tid] += t;
        __syncthreads();
    }
    if (tid < NCHUNK) psum[tid] = s[tid] - v;  // exclusive
}

__global__ void k_scan_c(const int* __restrict__ count, const int* __restrict__ loc,
                         const int* __restrict__ psum, int* __restrict__ rowptr,
                         float* __restrict__ dinv, int2* __restrict__ edata) {
    int n = blockIdx.x * blockDim.x + threadIdx.x;
    if (n >= N_NODES) return;
    int rp = loc[n] + psum[n >> 8];
    rowptr[n] = rp;
    float di = rsqrtf((float)count[n]);
    dinv[n] = di;
    edata[rp] = make_int2(n, __float_as_int(di * di));  // self-loop edge
    if (n == 0) rowptr[N_NODES] = E_TOT;
}

__global__ void k_scatter(const int* __restrict__ ei, const int* __restrict__ rowptr,
                          int* __restrict__ fill, const float* __restrict__ dinv,
                          int2* __restrict__ edata) {
    int e = blockIdx.x * blockDim.x + threadIdx.x;
    if (e >= N_EDGES) return;
    int s = ei[e], d = ei[N_EDGES + e];
    int p = rowptr[d] + atomicAdd(&fill[d], 1);
    edata[p] = make_int2(s, __float_as_int(dinv[s] * dinv[d]));
}

__device__ __forceinline__ h8 load_bfrag(const float* __restrict__ W, int ncols,
                                         int kbase, int c) {
    h8 r;
#pragma unroll
    for (int i = 0; i < 8; ++i) r[i] = (_Float16)W[(kbase + i) * ncols + c];
    return r;
}

__device__ __forceinline__ void unpack8(float4 raw, float* f) {
    const __half2* hp = (const __half2*)&raw;
#pragma unroll
    for (int i = 0; i < 4; ++i) {
        float2 t = __half22float2(hp[i]);
        f[2 * i] = t.x;
        f[2 * i + 1] = t.y;
    }
}

// 8 fp8 (e4m3) -> 8 fp32 via HW cvt_pk
__device__ __forceinline__ void unpack8_fp8(uint2 raw, float* f) {
    f32x2 t;
    t = __builtin_amdgcn_cvt_pk_f32_fp8(raw.x, false); f[0] = t[0]; f[1] = t[1];
    t = __builtin_amdgcn_cvt_pk_f32_fp8(raw.x, true);  f[2] = t[0]; f[3] = t[1];
    t = __builtin_amdgcn_cvt_pk_f32_fp8(raw.y, false); f[4] = t[0]; f[5] = t[1];
    t = __builtin_amdgcn_cvt_pk_f32_fp8(raw.y, true);  f[6] = t[0]; f[7] = t[1];
}

// 4 fp32 -> 4 fp8 bytes in one int
__device__ __forceinline__ int pack4_fp8(float a, float b, float c, float d) {
    int r = __builtin_amdgcn_cvt_pk_fp8_f32(a, b, 0, false);
    r = __builtin_amdgcn_cvt_pk_fp8_f32(c, d, r, true);
    return r;
}

// pack 4 fp32 -> 4 fp16 in 8 B
__device__ __forceinline__ float2 pack4(float a, float b, float c, float d) {
    union { __half2 h2[2]; float2 f2; } u;
    u.h2[0] = __floats2half2_rn(a, b);
    u.h2[1] = __floats2half2_rn(c, d);
    return u.f2;
}

// h = relu(x @ w1 + b1) -> xh[:,0,:] (fp16), via swapped-operand MFMA.
__global__ __launch_bounds__(256) void k_h_mfma(const float* __restrict__ x,
                                                const float* __restrict__ w1,
                                                const float* __restrict__ b1,
                                                __half* __restrict__ xh) {
    int lane = threadIdx.x & 63;
    int gw = blockIdx.x * 4 + (threadIdx.x >> 6);
    int krow = lane >> 4, col = lane & 15;
    h8 B[4][4];
#pragma unroll
    for (int ct = 0; ct < 4; ++ct)
#pragma unroll
        for (int s = 0; s < 4; ++s)
            B[ct][s] = load_bfrag(w1, HIDDEN, krow * 8 + 32 * s, ct * 16 + col);
    float4 bias[4];
#pragma unroll
    for (int ct = 0; ct < 4; ++ct) bias[ct] = *(const float4*)&b1[ct * 16 + krow * 4];
    for (int t = gw; t < NTILES; t += 1024) {
        int n0 = t * 16;
        const float* xrow = x + (size_t)(n0 + col) * IN_CH + krow * 8;
        f32x4 acc[4] = {{0.f, 0.f, 0.f, 0.f}, {0.f, 0.f, 0.f, 0.f},
                        {0.f, 0.f, 0.f, 0.f}, {0.f, 0.f, 0.f, 0.f}};
#pragma unroll
        for (int s = 0; s < 4; ++s) {
            float4 p0 = *(const float4*)(xrow + 32 * s);
            float4 p1 = *(const float4*)(xrow + 32 * s + 4);
            h8 a;
            a[0] = (_Float16)p0.x; a[1] = (_Float16)p0.y;
            a[2] = (_Float16)p0.z; a[3] = (_Float16)p0.w;
            a[4] = (_Float16)p1.x; a[5] = (_Float16)p1.y;
            a[6] = (_Float16)p1.z; a[7] = (_Float16)p1.w;
#pragma unroll
            for (int ct = 0; ct < 4; ++ct) acc[ct] = MFMA16(B[ct][s], a, acc[ct]);
        }
        __half* op = xh + (size_t)(n0 + col) * 320 + krow * 4;
#pragma unroll
        for (int ct = 0; ct < 4; ++ct) {
            float2 pk = pack4(fmaxf(acc[ct][0] + bias[ct].x, 0.f),
                              fmaxf(acc[ct][1] + bias[ct].y, 0.f),
                              fmaxf(acc[ct][2] + bias[ct].z, 0.f),
                              fmaxf(acc[ct][3] + bias[ct].w, 0.f));
            *(float2*)(op + ct * 16) = pk;
        }
    }
}

// Layer-1 v-only projection -> fp8 e4m3 (softmax over L=1 is identically 1).
__global__ __launch_bounds__(256) void k_v1_mfma(const __half* __restrict__ xh,
                                                 const float* __restrict__ wv,
                                                 unsigned char* __restrict__ vh1) {
    int lane = threadIdx.x & 63;
    int gw = blockIdx.x * 4 + (threadIdx.x >> 6);
    int krow = lane >> 4, col = lane & 15;
    h8 B[4][2];
#pragma unroll
    for (int ct = 0; ct < 4; ++ct)
#pragma unroll
        for (int s = 0; s < 2; ++s)
            B[ct][s] = load_bfrag(wv, HIDDEN, krow * 8 + 32 * s, ct * 16 + col);
    for (int t = gw; t < NTILES; t += QKV_WPR) {
        int n0 = t * 16;
        const __half* ap = xh + (size_t)(n0 + col) * 320 + krow * 8;  // row 0
        h8 a0 = *(const h8*)(const void*)ap;
        h8 a1 = *(const h8*)(const void*)(ap + 32);
        f32x4 acc[4] = {{0.f, 0.f, 0.f, 0.f}, {0.f, 0.f, 0.f, 0.f},
                        {0.f, 0.f, 0.f, 0.f}, {0.f, 0.f, 0.f, 0.f}};
#pragma unroll
        for (int ct = 0; ct < 4; ++ct) {
            acc[ct] = MFMA16(B[ct][0], a0, acc[ct]);
            acc[ct] = MFMA16(B[ct][1], a1, acc[ct]);
        }
        unsigned char* op = vh1 + (size_t)(n0 + col) * 64 + krow * 4;
#pragma unroll
        for (int ct = 0; ct < 4; ++ct)
            *(int*)(op + ct * 16) =
                pack4_fp8(acc[ct][0], acc[ct][1], acc[ct][2], acc[ct][3]);
    }
}

// Layer-1 edge kernel: pure normalized SpMV over fp8 vh1, 2-octet ILP.
__global__ __launch_bounds__(256) void k_edge_l1(const int* __restrict__ rowptr,
                                                 const int2* __restrict__ edata,
                                                 const unsigned char* __restrict__ vh1,
                                                 __half* __restrict__ xh) {
    int tid = threadIdx.x;
    int wid = tid >> 6, lane = tid & 63;
    int g = lane >> 3, r = lane & 7;
    int d = blockIdx.x * 4 + wid;
    if (d >= N_NODES) return;
    int rs = rowptr[d], re = rowptr[d + 1];
    float acc[8];
#pragma unroll
    for (int i = 0; i < 8; ++i) acc[i] = 0.f;
    int base = rs;
    for (; base + 8 < re; base += 16) {
        int ea = base + g, eb = base + 8 + g;
        bool va = ea < re, vb = eb < re;
        int2 e0 = edata[va ? ea : rs];
        int2 e1 = edata[vb ? eb : rs];
        float n0 = va ? __int_as_float(e0.y) : 0.f;
        float n1 = vb ? __int_as_float(e1.y) : 0.f;
        uint2 raw0 = *(const uint2*)(vh1 + (size_t)e0.x * 64 + r * 8);
        uint2 raw1 = *(const uint2*)(vh1 + (size_t)e1.x * 64 + r * 8);
        float f0[8], f1[8];
        unpack8_fp8(raw0, f0);
        unpack8_fp8(raw1, f1);
#pragma unroll
        for (int c = 0; c < 8; ++c) {
            acc[c] = fmaf(n0, f0[c], acc[c]);
            acc[c] = fmaf(n1, f1[c], acc[c]);
        }
    }
    if (base < re) {
        int ea = base + g;
        bool va = ea < re;
        int2 e0 = edata[va ? ea : rs];
        float n0 = va ? __int_as_float(e0.y) : 0.f;
        uint2 raw0 = *(const uint2*)(vh1 + (size_t)e0.x * 64 + r * 8);
        float f0[8];
        unpack8_fp8(raw0, f0);
#pragma unroll
        for (int c = 0; c < 8; ++c) acc[c] = fmaf(n0, f0[c], acc[c]);
    }
#pragma unroll
    for (int c = 0; c < 8; ++c) {
        acc[c] += __shfl_xor(acc[c], 8);
        acc[c] += __shfl_xor(acc[c], 16);
        acc[c] += __shfl_xor(acc[c], 32);
    }
    if (lane < 8) {
        __half hbuf[8];
#pragma unroll
        for (int c = 0; c < 8; ++c) hbuf[c] = __float2half(fmaxf(acc[c], 0.f));
        *(float4*)(xh + (size_t)d * 320 + 64 + r * 8) = *(float4*)hbuf;
    }
}

// kv (+q for the last row) projections via swapped-operand MFMA (L>=2).
// NEW kvi layout: [n][l][head][16 B: k0..k7 | v0..v7] -> edge reads ONE uint4
// per (edge, l) covering both k and v of its head.
template <int L>
__global__ __launch_bounds__(256) void k_qkv_mfma(const __half* __restrict__ xh,
                                                  const float* __restrict__ wq,
                                                  const float* __restrict__ wk,
                                                  const float* __restrict__ wv,
                                                  __half* __restrict__ qh,
                                                  unsigned char* __restrict__ kvi) {
    int lane = threadIdx.x & 63;
    int gw = blockIdx.x * 4 + (threadIdx.x >> 6);
    int lx = gw / QKV_WPR;
    int slot = gw - lx * QKV_WPR;
    int krow = lane >> 4, col = lane & 15;
    bool doq = (lx == L - 1);
    h8 Bk[4][2], Bv[4][2], Bq[4][2];
#pragma unroll
    for (int ct = 0; ct < 4; ++ct)
#pragma unroll
        for (int s = 0; s < 2; ++s) {
            Bk[ct][s] = load_bfrag(wk, HIDDEN, krow * 8 + 32 * s, ct * 16 + col);
            Bv[ct][s] = load_bfrag(wv, HIDDEN, krow * 8 + 32 * s, ct * 16 + col);
        }
    if (doq) {
#pragma unroll
        for (int ct = 0; ct < 4; ++ct)
#pragma unroll
            for (int s = 0; s < 2; ++s)
                Bq[ct][s] = load_bfrag(wq, HIDDEN, krow * 8 + 32 * s, ct * 16 + col);
    }
    for (int t = slot; t < NTILES; t += QKV_WPR) {
        int n0 = t * 16;
        const __half* ap = xh + (size_t)(n0 + col) * 320 + lx * 64 + krow * 8;
        h8 a0 = *(const h8*)(const void*)ap;
        h8 a1 = *(const h8*)(const void*)(ap + 32);
        f32x4 ak[4] = {{0.f, 0.f, 0.f, 0.f}, {0.f, 0.f, 0.f, 0.f},
                       {0.f, 0.f, 0.f, 0.f}, {0.f, 0.f, 0.f, 0.f}};
        f32x4 av[4] = {{0.f, 0.f, 0.f, 0.f}, {0.f, 0.f, 0.f, 0.f},
                       {0.f, 0.f, 0.f, 0.f}, {0.f, 0.f, 0.f, 0.f}};
#pragma unroll
        for (int ct = 0; ct < 4; ++ct) {
            ak[ct] = MFMA16(Bk[ct][0], a0, ak[ct]);
            ak[ct] = MFMA16(Bk[ct][1], a1, ak[ct]);
            av[ct] = MFMA16(Bv[ct][0], a0, av[ct]);
            av[ct] = MFMA16(Bv[ct][1], a1, av[ct]);
        }
        // channels ct*16 + krow*4 + 0..3 -> head = ct*2 + (krow>>1),
        // within-head byte = (krow&1)*4
        unsigned char* opb = kvi + ((size_t)(n0 + col) * L + lx) * 128;
        int sub = (krow & 1) * 4;
#pragma unroll
        for (int ct = 0; ct < 4; ++ct) {
            int h = ct * 2 + (krow >> 1);
            *(int*)(opb + h * 16 + sub) =
                pack4_fp8(ak[ct][0], ak[ct][1], ak[ct][2], ak[ct][3]);
            *(int*)(opb + h * 16 + 8 + sub) =
                pack4_fp8(av[ct][0], av[ct][1], av[ct][2], av[ct][3]);
        }
        if (doq) {
            f32x4 aq[4] = {{0.f, 0.f, 0.f, 0.f}, {0.f, 0.f, 0.f, 0.f},
                           {0.f, 0.f, 0.f, 0.f}, {0.f, 0.f, 0.f, 0.f}};
#pragma unroll
            for (int ct = 0; ct < 4; ++ct) {
                aq[ct] = MFMA16(Bq[ct][0], a0, aq[ct]);
                aq[ct] = MFMA16(Bq[ct][1], a1, aq[ct]);
            }
            const float scl = 0.35355339059327373f;
            __half* qp = qh + (size_t)(n0 + col) * 64 + krow * 4;
#pragma unroll
            for (int ct = 0; ct < 4; ++ct)
                *(float2*)(qp + ct * 16) = pack4(aq[ct][0] * scl, aq[ct][1] * scl,
                                                 aq[ct][2] * scl, aq[ct][3] * scl);
        }
    }
}

// attention+accumulate for one octet's loaded kv (kv[l] = 16B: k|v of this head)
template <int L>
__device__ __forceinline__ void attn_acc(const uint4* kv, float nrm,
                                         const float* qf, float* acc) {
    float sc[L];
#pragma unroll
    for (int l = 0; l < L; ++l) {
        float kf[8];
        unpack8_fp8(make_uint2(kv[l].x, kv[l].y), kf);
        float p = 0.f;
#pragma unroll
        for (int c = 0; c < 8; ++c) p = fmaf(qf[c], kf[c], p);
        sc[l] = p;
    }
    float m = sc[0];
#pragma unroll
    for (int l = 1; l < L; ++l) m = fmaxf(m, sc[l]);
    float ssum = 0.f;
#pragma unroll
    for (int l = 0; l < L; ++l) { sc[l] = __expf(sc[l] - m); ssum += sc[l]; }
    float w = __fdividef(nrm, ssum);
#pragma unroll
    for (int l = 0; l < L; ++l) {
        float swl = sc[l] * w;
        float vf[8];
        unpack8_fp8(make_uint2(kv[l].z, kv[l].w), vf);
#pragma unroll
        for (int c = 0; c < 8; ++c) acc[c] = fmaf(swl, vf[c], acc[c]);
    }
}

// CSR edge kernel, 8 edges per octet, 2 octets in flight. One uint4 load per
// (edge, l) covers both k and v of lane's head.
template <int L>
__global__ __launch_bounds__(256) void k_edge_csr8(const int* __restrict__ rowptr,
                                                   const int2* __restrict__ edata,
                                                   const unsigned char* __restrict__ kvi,
                                                   const __half* __restrict__ qh,
                                                   float* __restrict__ aggout,
                                                   __half* __restrict__ xh) {
    int tid = threadIdx.x;
    int wid = tid >> 6, lane = tid & 63;
    int g = lane >> 3, r = lane & 7;
    int d = blockIdx.x * 4 + wid;
    if (d >= N_NODES) return;
    int rs = rowptr[d], re = rowptr[d + 1];
    float qf[8];
    unpack8(((const float4*)(qh + (size_t)d * 64))[r], qf);
    float acc[8];
#pragma unroll
    for (int i = 0; i < 8; ++i) acc[i] = 0.f;
    int base = rs;
    for (; base + 8 < re; base += 16) {
        int ea = base + g, eb = base + 8 + g;
        bool va = ea < re, vb = eb < re;
        int2 e0 = edata[va ? ea : rs];
        int2 e1 = edata[vb ? eb : rs];
        float n0 = va ? __int_as_float(e0.y) : 0.f;
        float n1 = vb ? __int_as_float(e1.y) : 0.f;
        const unsigned char* kb0 = kvi + (size_t)e0.x * (L * 128) + r * 16;
        const unsigned char* kb1 = kvi + (size_t)e1.x * (L * 128) + r * 16;
        uint4 kv0[L], kv1[L];
#pragma unroll
        for (int l = 0; l < L; ++l) {
            kv0[l] = *(const uint4*)(kb0 + l * 128);
            kv1[l] = *(const uint4*)(kb1 + l * 128);
        }
        attn_acc<L>(kv0, n0, qf, acc);
        attn_acc<L>(kv1, n1, qf, acc);
    }
    if (base < re) {
        int ea = base + g;
        bool va = ea < re;
        int2 e0 = edata[va ? ea : rs];
        float n0 = va ? __int_as_float(e0.y) : 0.f;
        const unsigned char* kb0 = kvi + (size_t)e0.x * (L * 128) + r * 16;
        uint4 kv0[L];
#pragma unroll
        for (int l = 0; l < L; ++l) kv0[l] = *(const uint4*)(kb0 + l * 128);
        attn_acc<L>(kv0, n0, qf, acc);
    }
#pragma unroll
    for (int c = 0; c < 8; ++c) {
        acc[c] += __shfl_xor(acc[c], 8);
        acc[c] += __shfl_xor(acc[c], 16);
        acc[c] += __shfl_xor(acc[c], 32);
    }
    if (lane < 8) {  // g==0, r==lane
        if (L == NUM_LAYERS) {
            float4 o0, o1;
            o0.x = fmaxf(acc[0], 0.f); o0.y = fmaxf(acc[1], 0.f);
            o0.z = fmaxf(acc[2], 0.f); o0.w = fmaxf(acc[3], 0.f);
            o1.x = fmaxf(acc[4], 0.f); o1.y = fmaxf(acc[5], 0.f);
            o1.z = fmaxf(acc[6], 0.f); o1.w = fmaxf(acc[7], 0.f);
            float4* op = (float4*)(aggout + (size_t)d * 64 + r * 8);
            op[0] = o0; op[1] = o1;
        } else {
            __half hbuf[8];
#pragma unroll
            for (int c = 0; c < 8; ++c) hbuf[c] = __float2half(fmaxf(acc[c], 0.f));
            *(float4*)(xh + (size_t)d * 320 + L * 64 + r * 8) = *(float4*)hbuf;
        }
    }
}

// logits = aggout @ w2 + b2; out = log_softmax(logits)
__global__ __launch_bounds__(256) void k_final_lds(const float* __restrict__ aggout,
                                                   const float* __restrict__ w2,
                                                   const float* __restrict__ b2,
                                                   float* __restrict__ out) {
    __shared__ float rows[16][HIDDEN];
    int tid = threadIdx.x, wid = tid >> 6, lane = tid & 63;
    int cl = (lane < OUT_CH) ? lane : (OUT_CH - 1);
    float wcol[HIDDEN];
#pragma unroll
    for (int j = 0; j < HIDDEN; ++j) wcol[j] = w2[j * OUT_CH + cl];
    float b = b2[cl];
    for (int t = blockIdx.x; t < NTILES; t += gridDim.x) {
        int n0 = t * 16;
        {
            int rr = tid >> 4, seg = tid & 15;
            *(float4*)&rows[rr][seg * 4] =
                *(const float4*)&aggout[(size_t)(n0 + rr) * 64 + seg * 4];
        }
        __syncthreads();
#pragma unroll
        for (int u = 0; u < 4; ++u) {
            int ln = wid * 4 + u;
            const float4* rp = (const float4*)rows[ln];
            float a0 = 0.f, a1 = 0.f, a2 = 0.f, a3 = 0.f;
#pragma unroll
            for (int jc = 0; jc < HIDDEN / 4; ++jc) {
                float4 r = rp[jc];
                a0 = fmaf(r.x, wcol[jc * 4 + 0], a0);
                a1 = fmaf(r.y, wcol[jc * 4 + 1], a1);
                a2 = fmaf(r.z, wcol[jc * 4 + 2], a2);
                a3 = fmaf(r.w, wcol[jc * 4 + 3], a3);
            }
            float logit = (lane < OUT_CH) ? ((a0 + a1) + (a2 + a3) + b) : -INFINITY;
            float m = logit;
            for (int mask = 32; mask; mask >>= 1) m = fmaxf(m, __shfl_xor(m, mask));
            float ex = (lane < OUT_CH) ? __expf(logit - m) : 0.f;
            float ssum = ex;
            for (int mask = 32; mask; mask >>= 1) ssum += __shfl_xor(ssum, mask);
            if (lane < OUT_CH)
                out[(size_t)(n0 + ln) * OUT_CH + lane] = logit - m - logf(ssum);
        }
        __syncthreads();
    }
}

extern "C" void kernel_launch(void* const* d_in, const int* in_sizes, int n_in,
                              void* d_out, int out_size, void* d_ws, size_t ws_size,
                              hipStream_t stream) {
    const float* x  = (const float*)d_in[0];
    const int*   ei = (const int*)d_in[1];
    // d_in[2] = heads (known 8)
    const float* w1 = (const float*)d_in[3];
    const float* b1 = (const float*)d_in[4];
    const float* wq = (const float*)d_in[5];
    const float* wk = (const float*)d_in[6];
    const float* wv = (const float*)d_in[7];
    const float* w2 = (const float*)d_in[8];
    const float* b2 = (const float*)d_in[9];
    float* out = (float*)d_out;

    char* cur = (char*)d_ws;
    auto alloc = [&](size_t bytes) { char* p = cur; cur += (bytes + 255) & ~(size_t)255; return p; };
    float*         dinv   = (float*)alloc(N_NODES * 4);
    __half*        xh     = (__half*)alloc((size_t)N_NODES * 320 * 2);
    float*         aggout = (float*)alloc((size_t)N_NODES * 64 * 4);
    __half*        qh     = (__half*)alloc((size_t)N_NODES * 64 * 2);
    unsigned char* kvi    = (unsigned char*)alloc((size_t)N_NODES * NUM_LAYERS * 128);
    unsigned char* vh1    = (unsigned char*)alloc((size_t)N_NODES * 64);
    int*           count  = (int*)alloc(N_NODES * 4);
    int*           loc    = (int*)alloc(N_NODES * 4);
    int*           psum   = (int*)alloc(256 * 4);
    int*           rowptr = (int*)alloc((N_NODES + 1) * 4);
    int*           fill   = (int*)alloc(N_NODES * 4);
    int2*          edata  = (int2*)alloc((size_t)E_TOT * 8);

    // CSR build (once)
    k_count_init<<<(N_NODES + 255) / 256, 256, 0, stream>>>(count, fill);
    k_count<<<(N_EDGES + 255) / 256, 256, 0, stream>>>(ei + N_EDGES, count);
    k_scan_a<<<NCHUNK, 256, 0, stream>>>(count, loc, psum);
    k_scan_b<<<1, 256, 0, stream>>>(psum);
    k_scan_c<<<(N_NODES + 255) / 256, 256, 0, stream>>>(count, loc, psum, rowptr,
                                                        dinv, edata);
    k_scatter<<<(N_EDGES + 255) / 256, 256, 0, stream>>>(ei, rowptr, fill, dinv, edata);

    k_h_mfma<<<256, 256, 0, stream>>>(x, w1, b1, xh);

    // Layer 1 (L=1): softmax over a single slot == 1; only v matters.
    k_v1_mfma<<<QKV_WPR / 4, 256, 0, stream>>>(xh, wv, vh1);
    k_edge_l1<<<(N_NODES + 3) / 4, 256, 0, stream>>>(rowptr, edata, vh1, xh);

    for (int i = 1; i < NUM_LAYERS; ++i) {
        int L = i + 1;
        int qkvblk = L * (QKV_WPR / 4);
        const float* wqi = wq + i * 4096;
        const float* wki = wk + i * 4096;
        const float* wvi = wv + i * 4096;
        switch (L) {
            case 2:
                k_qkv_mfma<2><<<qkvblk, 256, 0, stream>>>(xh, wqi, wki, wvi, qh, kvi);
                k_edge_csr8<2><<<(N_NODES + 3) / 4, 256, 0, stream>>>(rowptr, edata, kvi, qh, aggout, xh);
                break;
            case 3:
                k_qkv_mfma<3><<<qkvblk, 256, 0, stream>>>(xh, wqi, wki, wvi, qh, kvi);
                k_edge_csr8<3><<<(N_NODES + 3) / 4, 256, 0, stream>>>(rowptr, edata, kvi, qh, aggout, xh);
                break;
            default:
                k_qkv_mfma<4><<<qkvblk, 256, 0, stream>>>(xh, wqi, wki, wvi, qh, kvi);
                k_edge_csr8<4><<<(N_NODES + 3) / 4, 256, 0, stream>>>(rowptr, edata, kvi, qh, aggout, xh);
                break;
        }
    }
    k_final_lds<<<512, 256, 0, stream>>>(aggout, w2, b2, out);
}

// Round 13
// 247.932 us; speedup vs baseline: 1.0639x; 1.0639x over previous
//
#include <hip/hip_runtime.h>
#include <hip/hip_fp16.h>
#include <math.h>

#define N_NODES 50000
#define N_EDGES 300000
#define E_TOT (N_EDGES + N_NODES)
#define IN_CH 128
#define HIDDEN 64
#define OUT_CH 40
#define NUM_LAYERS 4
#define NCHUNK ((N_NODES + 255) / 256)  // 196
#define NTILES (N_NODES / 16)           // 3125 (exact)
#define QKV_WPR 512                     // waves per role in k_qkv_mfma
// heads = 8, d_head = 8, scale = 1/sqrt(8)

typedef _Float16 h8 __attribute__((ext_vector_type(8)));
typedef float f32x4 __attribute__((ext_vector_type(4)));
typedef float f32x2 __attribute__((ext_vector_type(2)));

#define MFMA16(a, b, c) __builtin_amdgcn_mfma_f32_16x16x32_f16((a), (b), (c), 0, 0, 0)

__global__ void k_count_init(int* count, int* fill) {
    int n = blockIdx.x * blockDim.x + threadIdx.x;
    if (n < N_NODES) { count[n] = 1; fill[n] = 1; }  // slot 0 = self-loop
}

__global__ void k_count(const int* __restrict__ dst, int* count) {
    int e = blockIdx.x * blockDim.x + threadIdx.x;
    if (e < N_EDGES) atomicAdd(&count[dst[e]], 1);
}

__global__ __launch_bounds__(256) void k_scan_a(const int* __restrict__ count,
                                                int* __restrict__ loc,
                                                int* __restrict__ psum) {
    __shared__ int s[256];
    int tid = threadIdx.x;
    int g = blockIdx.x * 256 + tid;
    int v = (g < N_NODES) ? count[g] : 0;
    s[tid] = v;
    __syncthreads();
    for (int off = 1; off < 256; off <<= 1) {
        int t = (tid >= off) ? s[tid - off] : 0;
        __syncthreads();
        s[tid] += t;
        __syncthreads();
    }
    if (g < N_NODES) loc[g] = s[tid] - v;  // exclusive
    if (tid == 255) psum[blockIdx.x] = s[255];
}

__global__ __launch_bounds__(256) void k_scan_b(int* psum) {
    __shared__ int s[256];
    int tid = threadIdx.x;
    int v = (tid < NCHUNK) ? psum[tid] : 0;
    s[tid] = v;
    __syncthreads();
    for (int off = 1; off < 256; off <<= 1) {
        int t = (tid >= off) ? s[tid - off] : 0;
        __syncthreads();
        s[tid] += t;
        __syncthreads();
    }
    if (tid < NCHUNK) psum[tid] = s[tid] - v;  // exclusive
}

__global__ void k_scan_c(const int* __restrict__ count, const int* __restrict__ loc,
                         const int* __restrict__ psum, int* __restrict__ rowptr,
                         float* __restrict__ dinv, int2* __restrict__ edata) {
    int n = blockIdx.x * blockDim.x + threadIdx.x;
    if (n >= N_NODES) return;
    int rp = loc[n] + psum[n >> 8];
    rowptr[n] = rp;
    float di = rsqrtf((float)count[n]);
    dinv[n] = di;
    edata[rp] = make_int2(n, __float_as_int(di * di));  // self-loop edge
    if (n == 0) rowptr[N_NODES] = E_TOT;
}

__global__ void k_scatter(const int* __restrict__ ei, const int* __restrict__ rowptr,
                          int* __restrict__ fill, const float* __restrict__ dinv,
                          int2* __restrict__ edata) {
    int e = blockIdx.x * blockDim.x + threadIdx.x;
    if (e >= N_EDGES) return;
    int s = ei[e], d = ei[N_EDGES + e];
    int p = rowptr[d] + atomicAdd(&fill[d], 1);
    edata[p] = make_int2(s, __float_as_int(dinv[s] * dinv[d]));
}

__device__ __forceinline__ h8 load_bfrag(const float* __restrict__ W, int ncols,
                                         int kbase, int c) {
    h8 r;
#pragma unroll
    for (int i = 0; i < 8; ++i) r[i] = (_Float16)W[(kbase + i) * ncols + c];
    return r;
}

__device__ __forceinline__ void unpack8(float4 raw, float* f) {
    const __half2* hp = (const __half2*)&raw;
#pragma unroll
    for (int i = 0; i < 4; ++i) {
        float2 t = __half22float2(hp[i]);
        f[2 * i] = t.x;
        f[2 * i + 1] = t.y;
    }
}

// 8 fp8 (e4m3) -> 8 fp32 via HW cvt_pk
__device__ __forceinline__ void unpack8_fp8(uint2 raw, float* f) {
    f32x2 t;
    t = __builtin_amdgcn_cvt_pk_f32_fp8(raw.x, false); f[0] = t[0]; f[1] = t[1];
    t = __builtin_amdgcn_cvt_pk_f32_fp8(raw.x, true);  f[2] = t[0]; f[3] = t[1];
    t = __builtin_amdgcn_cvt_pk_f32_fp8(raw.y, false); f[4] = t[0]; f[5] = t[1];
    t = __builtin_amdgcn_cvt_pk_f32_fp8(raw.y, true);  f[6] = t[0]; f[7] = t[1];
}

// 4 fp32 -> 4 fp8 bytes in one int
__device__ __forceinline__ int pack4_fp8(float a, float b, float c, float d) {
    int r = __builtin_amdgcn_cvt_pk_fp8_f32(a, b, 0, false);
    r = __builtin_amdgcn_cvt_pk_fp8_f32(c, d, r, true);
    return r;
}

// pack 4 fp32 -> 4 fp16 in 8 B
__device__ __forceinline__ float2 pack4(float a, float b, float c, float d) {
    union { __half2 h2[2]; float2 f2; } u;
    u.h2[0] = __floats2half2_rn(a, b);
    u.h2[1] = __floats2half2_rn(c, d);
    return u.f2;
}

// h = relu(x @ w1 + b1) -> xh[:,0,:] (fp16), via swapped-operand MFMA.
__global__ __launch_bounds__(256) void k_h_mfma(const float* __restrict__ x,
                                                const float* __restrict__ w1,
                                                const float* __restrict__ b1,
                                                __half* __restrict__ xh) {
    int lane = threadIdx.x & 63;
    int gw = blockIdx.x * 4 + (threadIdx.x >> 6);
    int krow = lane >> 4, col = lane & 15;
    h8 B[4][4];
#pragma unroll
    for (int ct = 0; ct < 4; ++ct)
#pragma unroll
        for (int s = 0; s < 4; ++s)
            B[ct][s] = load_bfrag(w1, HIDDEN, krow * 8 + 32 * s, ct * 16 + col);
    float4 bias[4];
#pragma unroll
    for (int ct = 0; ct < 4; ++ct) bias[ct] = *(const float4*)&b1[ct * 16 + krow * 4];
    for (int t = gw; t < NTILES; t += 1024) {
        int n0 = t * 16;
        const float* xrow = x + (size_t)(n0 + col) * IN_CH + krow * 8;
        f32x4 acc[4] = {{0.f, 0.f, 0.f, 0.f}, {0.f, 0.f, 0.f, 0.f},
                        {0.f, 0.f, 0.f, 0.f}, {0.f, 0.f, 0.f, 0.f}};
#pragma unroll
        for (int s = 0; s < 4; ++s) {
            float4 p0 = *(const float4*)(xrow + 32 * s);
            float4 p1 = *(const float4*)(xrow + 32 * s + 4);
            h8 a;
            a[0] = (_Float16)p0.x; a[1] = (_Float16)p0.y;
            a[2] = (_Float16)p0.z; a[3] = (_Float16)p0.w;
            a[4] = (_Float16)p1.x; a[5] = (_Float16)p1.y;
            a[6] = (_Float16)p1.z; a[7] = (_Float16)p1.w;
#pragma unroll
            for (int ct = 0; ct < 4; ++ct) acc[ct] = MFMA16(B[ct][s], a, acc[ct]);
        }
        __half* op = xh + (size_t)(n0 + col) * 320 + krow * 4;
#pragma unroll
        for (int ct = 0; ct < 4; ++ct) {
            float2 pk = pack4(fmaxf(acc[ct][0] + bias[ct].x, 0.f),
                              fmaxf(acc[ct][1] + bias[ct].y, 0.f),
                              fmaxf(acc[ct][2] + bias[ct].z, 0.f),
                              fmaxf(acc[ct][3] + bias[ct].w, 0.f));
            *(float2*)(op + ct * 16) = pk;
        }
    }
}

// Layer-1 v-only projection -> fp8 e4m3 (softmax over L=1 is identically 1).
__global__ __launch_bounds__(256) void k_v1_mfma(const __half* __restrict__ xh,
                                                 const float* __restrict__ wv,
                                                 unsigned char* __restrict__ vh1) {
    int lane = threadIdx.x & 63;
    int gw = blockIdx.x * 4 + (threadIdx.x >> 6);
    int krow = lane >> 4, col = lane & 15;
    h8 B[4][2];
#pragma unroll
    for (int ct = 0; ct < 4; ++ct)
#pragma unroll
        for (int s = 0; s < 2; ++s)
            B[ct][s] = load_bfrag(wv, HIDDEN, krow * 8 + 32 * s, ct * 16 + col);
    for (int t = gw; t < NTILES; t += QKV_WPR) {
        int n0 = t * 16;
        const __half* ap = xh + (size_t)(n0 + col) * 320 + krow * 8;  // row 0
        h8 a0 = *(const h8*)(const void*)ap;
        h8 a1 = *(const h8*)(const void*)(ap + 32);
        f32x4 acc[4] = {{0.f, 0.f, 0.f, 0.f}, {0.f, 0.f, 0.f, 0.f},
                        {0.f, 0.f, 0.f, 0.f}, {0.f, 0.f, 0.f, 0.f}};
#pragma unroll
        for (int ct = 0; ct < 4; ++ct) {
            acc[ct] = MFMA16(B[ct][0], a0, acc[ct]);
            acc[ct] = MFMA16(B[ct][1], a1, acc[ct]);
        }
        unsigned char* op = vh1 + (size_t)(n0 + col) * 64 + krow * 4;
#pragma unroll
        for (int ct = 0; ct < 4; ++ct)
            *(int*)(op + ct * 16) =
                pack4_fp8(acc[ct][0], acc[ct][1], acc[ct][2], acc[ct][3]);
    }
}

// Layer-1 edge kernel: pure normalized SpMV over fp8 vh1, 2-octet ILP.
__global__ __launch_bounds__(256) void k_edge_l1(const int* __restrict__ rowptr,
                                                 const int2* __restrict__ edata,
                                                 const unsigned char* __restrict__ vh1,
                                                 __half* __restrict__ xh) {
    int tid = threadIdx.x;
    int wid = tid >> 6, lane = tid & 63;
    int g = lane >> 3, r = lane & 7;
    int d = blockIdx.x * 4 + wid;
    if (d >= N_NODES) return;
    int rs = rowptr[d], re = rowptr[d + 1];
    float acc[8];
#pragma unroll
    for (int i = 0; i < 8; ++i) acc[i] = 0.f;
    int base = rs;
    for (; base + 8 < re; base += 16) {
        int ea = base + g, eb = base + 8 + g;
        bool va = ea < re, vb = eb < re;
        int2 e0 = edata[va ? ea : rs];
        int2 e1 = edata[vb ? eb : rs];
        float n0 = va ? __int_as_float(e0.y) : 0.f;
        float n1 = vb ? __int_as_float(e1.y) : 0.f;
        uint2 raw0 = *(const uint2*)(vh1 + (size_t)e0.x * 64 + r * 8);
        uint2 raw1 = *(const uint2*)(vh1 + (size_t)e1.x * 64 + r * 8);
        float f0[8], f1[8];
        unpack8_fp8(raw0, f0);
        unpack8_fp8(raw1, f1);
#pragma unroll
        for (int c = 0; c < 8; ++c) {
            acc[c] = fmaf(n0, f0[c], acc[c]);
            acc[c] = fmaf(n1, f1[c], acc[c]);
        }
    }
    if (base < re) {
        int ea = base + g;
        bool va = ea < re;
        int2 e0 = edata[va ? ea : rs];
        float n0 = va ? __int_as_float(e0.y) : 0.f;
        uint2 raw0 = *(const uint2*)(vh1 + (size_t)e0.x * 64 + r * 8);
        float f0[8];
        unpack8_fp8(raw0, f0);
#pragma unroll
        for (int c = 0; c < 8; ++c) acc[c] = fmaf(n0, f0[c], acc[c]);
    }
#pragma unroll
    for (int c = 0; c < 8; ++c) {
        acc[c] += __shfl_xor(acc[c], 8);
        acc[c] += __shfl_xor(acc[c], 16);
        acc[c] += __shfl_xor(acc[c], 32);
    }
    if (lane < 8) {
        __half hbuf[8];
#pragma unroll
        for (int c = 0; c < 8; ++c) hbuf[c] = __float2half(fmaxf(acc[c], 0.f));
        *(float4*)(xh + (size_t)d * 320 + 64 + r * 8) = *(float4*)hbuf;
    }
}

// kv (+q for the last row) projections via swapped-operand MFMA (L>=2).
// Role lx computes k,v of input row lx -> fp8 e4m3; role L-1 also computes q.
template <int L>
__global__ __launch_bounds__(256) void k_qkv_mfma(const __half* __restrict__ xh,
                                                  const float* __restrict__ wq,
                                                  const float* __restrict__ wk,
                                                  const float* __restrict__ wv,
                                                  __half* __restrict__ qh,
                                                  unsigned char* __restrict__ kvi) {
    int lane = threadIdx.x & 63;
    int gw = blockIdx.x * 4 + (threadIdx.x >> 6);
    int lx = gw / QKV_WPR;
    int slot = gw - lx * QKV_WPR;
    int krow = lane >> 4, col = lane & 15;
    bool doq = (lx == L - 1);
    h8 Bk[4][2], Bv[4][2], Bq[4][2];
#pragma unroll
    for (int ct = 0; ct < 4; ++ct)
#pragma unroll
        for (int s = 0; s < 2; ++s) {
            Bk[ct][s] = load_bfrag(wk, HIDDEN, krow * 8 + 32 * s, ct * 16 + col);
            Bv[ct][s] = load_bfrag(wv, HIDDEN, krow * 8 + 32 * s, ct * 16 + col);
        }
    if (doq) {
#pragma unroll
        for (int ct = 0; ct < 4; ++ct)
#pragma unroll
            for (int s = 0; s < 2; ++s)
                Bq[ct][s] = load_bfrag(wq, HIDDEN, krow * 8 + 32 * s, ct * 16 + col);
    }
    for (int t = slot; t < NTILES; t += QKV_WPR) {
        int n0 = t * 16;
        const __half* ap = xh + (size_t)(n0 + col) * 320 + lx * 64 + krow * 8;
        h8 a0 = *(const h8*)(const void*)ap;
        h8 a1 = *(const h8*)(const void*)(ap + 32);
        f32x4 ak[4] = {{0.f, 0.f, 0.f, 0.f}, {0.f, 0.f, 0.f, 0.f},
                       {0.f, 0.f, 0.f, 0.f}, {0.f, 0.f, 0.f, 0.f}};
        f32x4 av[4] = {{0.f, 0.f, 0.f, 0.f}, {0.f, 0.f, 0.f, 0.f},
                       {0.f, 0.f, 0.f, 0.f}, {0.f, 0.f, 0.f, 0.f}};
#pragma unroll
        for (int ct = 0; ct < 4; ++ct) {
            ak[ct] = MFMA16(Bk[ct][0], a0, ak[ct]);
            ak[ct] = MFMA16(Bk[ct][1], a1, ak[ct]);
            av[ct] = MFMA16(Bv[ct][0], a0, av[ct]);
            av[ct] = MFMA16(Bv[ct][1], a1, av[ct]);
        }
        unsigned char* op = kvi + ((size_t)(n0 + col) * L + lx) * 128 + krow * 4;
#pragma unroll
        for (int ct = 0; ct < 4; ++ct) {
            *(int*)(op + ct * 16) = pack4_fp8(ak[ct][0], ak[ct][1], ak[ct][2], ak[ct][3]);
            *(int*)(op + 64 + ct * 16) = pack4_fp8(av[ct][0], av[ct][1], av[ct][2], av[ct][3]);
        }
        if (doq) {
            f32x4 aq[4] = {{0.f, 0.f, 0.f, 0.f}, {0.f, 0.f, 0.f, 0.f},
                           {0.f, 0.f, 0.f, 0.f}, {0.f, 0.f, 0.f, 0.f}};
#pragma unroll
            for (int ct = 0; ct < 4; ++ct) {
                aq[ct] = MFMA16(Bq[ct][0], a0, aq[ct]);
                aq[ct] = MFMA16(Bq[ct][1], a1, aq[ct]);
            }
            const float scl = 0.35355339059327373f;
            __half* qp = qh + (size_t)(n0 + col) * 64 + krow * 4;
#pragma unroll
            for (int ct = 0; ct < 4; ++ct)
                *(float2*)(qp + ct * 16) = pack4(aq[ct][0] * scl, aq[ct][1] * scl,
                                                 aq[ct][2] * scl, aq[ct][3] * scl);
        }
    }
}

// attention+accumulate for one octet's loaded kv
template <int L>
__device__ __forceinline__ void attn_acc(const uint2* kraw, const uint2* vraw,
                                         float nrm, const float* qf, float* acc) {
    float sc[L];
#pragma unroll
    for (int l = 0; l < L; ++l) {
        float kf[8];
        unpack8_fp8(kraw[l], kf);
        float p = 0.f;
#pragma unroll
        for (int c = 0; c < 8; ++c) p = fmaf(qf[c], kf[c], p);
        sc[l] = p;
    }
    float m = sc[0];
#pragma unroll
    for (int l = 1; l < L; ++l) m = fmaxf(m, sc[l]);
    float ssum = 0.f;
#pragma unroll
    for (int l = 0; l < L; ++l) { sc[l] = __expf(sc[l] - m); ssum += sc[l]; }
    float w = __fdividef(nrm, ssum);
#pragma unroll
    for (int l = 0; l < L; ++l) {
        float swl = sc[l] * w;
        float vf[8];
        unpack8_fp8(vraw[l], vf);
#pragma unroll
        for (int c = 0; c < 8; ++c) acc[c] = fmaf(swl, vf[c], acc[c]);
    }
}

// CSR edge kernel, 8 edges per octet, 2 octets in flight (ILP).
// Subgroup g (8 lanes) owns edge base+g; lane r owns head r. kv = fp8 e4m3.
template <int L>
__global__ __launch_bounds__(256) void k_edge_csr8(const int* __restrict__ rowptr,
                                                   const int2* __restrict__ edata,
                                                   const unsigned char* __restrict__ kvi,
                                                   const __half* __restrict__ qh,
                                                   float* __restrict__ aggout,
                                                   __half* __restrict__ xh) {
    int tid = threadIdx.x;
    int wid = tid >> 6, lane = tid & 63;
    int g = lane >> 3, r = lane & 7;
    int d = blockIdx.x * 4 + wid;
    if (d >= N_NODES) return;
    int rs = rowptr[d], re = rowptr[d + 1];
    float qf[8];
    unpack8(((const float4*)(qh + (size_t)d * 64))[r], qf);
    float acc[8];
#pragma unroll
    for (int i = 0; i < 8; ++i) acc[i] = 0.f;
    int base = rs;
    for (; base + 8 < re; base += 16) {
        int ea = base + g, eb = base + 8 + g;
        bool va = ea < re, vb = eb < re;
        int2 e0 = edata[va ? ea : rs];
        int2 e1 = edata[vb ? eb : rs];
        float n0 = va ? __int_as_float(e0.y) : 0.f;
        float n1 = vb ? __int_as_float(e1.y) : 0.f;
        const unsigned char* kb0 = kvi + (size_t)e0.x * (L * 128) + r * 8;
        const unsigned char* kb1 = kvi + (size_t)e1.x * (L * 128) + r * 8;
        uint2 kraw0[L], vraw0[L], kraw1[L], vraw1[L];
#pragma unroll
        for (int l = 0; l < L; ++l) {
            kraw0[l] = *(const uint2*)(kb0 + l * 128);
            vraw0[l] = *(const uint2*)(kb0 + l * 128 + 64);
            kraw1[l] = *(const uint2*)(kb1 + l * 128);
            vraw1[l] = *(const uint2*)(kb1 + l * 128 + 64);
        }
        attn_acc<L>(kraw0, vraw0, n0, qf, acc);
        attn_acc<L>(kraw1, vraw1, n1, qf, acc);
    }
    if (base < re) {
        int ea = base + g;
        bool va = ea < re;
        int2 e0 = edata[va ? ea : rs];
        float n0 = va ? __int_as_float(e0.y) : 0.f;
        const unsigned char* kb0 = kvi + (size_t)e0.x * (L * 128) + r * 8;
        uint2 kraw0[L], vraw0[L];
#pragma unroll
        for (int l = 0; l < L; ++l) {
            kraw0[l] = *(const uint2*)(kb0 + l * 128);
            vraw0[l] = *(const uint2*)(kb0 + l * 128 + 64);
        }
        attn_acc<L>(kraw0, vraw0, n0, qf, acc);
    }
#pragma unroll
    for (int c = 0; c < 8; ++c) {
        acc[c] += __shfl_xor(acc[c], 8);
        acc[c] += __shfl_xor(acc[c], 16);
        acc[c] += __shfl_xor(acc[c], 32);
    }
    if (lane < 8) {  // g==0, r==lane
        if (L == NUM_LAYERS) {
            float4 o0, o1;
            o0.x = fmaxf(acc[0], 0.f); o0.y = fmaxf(acc[1], 0.f);
            o0.z = fmaxf(acc[2], 0.f); o0.w = fmaxf(acc[3], 0.f);
            o1.x = fmaxf(acc[4], 0.f); o1.y = fmaxf(acc[5], 0.f);
            o1.z = fmaxf(acc[6], 0.f); o1.w = fmaxf(acc[7], 0.f);
            float4* op = (float4*)(aggout + (size_t)d * 64 + r * 8);
            op[0] = o0; op[1] = o1;
        } else {
            __half hbuf[8];
#pragma unroll
            for (int c = 0; c < 8; ++c) hbuf[c] = __float2half(fmaxf(acc[c], 0.f));
            *(float4*)(xh + (size_t)d * 320 + L * 64 + r * 8) = *(float4*)hbuf;
        }
    }
}

// logits = aggout @ w2 + b2; out = log_softmax(logits)
__global__ __launch_bounds__(256) void k_final_lds(const float* __restrict__ aggout,
                                                   const float* __restrict__ w2,
                                                   const float* __restrict__ b2,
                                                   float* __restrict__ out) {
    __shared__ float rows[16][HIDDEN];
    int tid = threadIdx.x, wid = tid >> 6, lane = tid & 63;
    int cl = (lane < OUT_CH) ? lane : (OUT_CH - 1);
    float wcol[HIDDEN];
#pragma unroll
    for (int j = 0; j < HIDDEN; ++j) wcol[j] = w2[j * OUT_CH + cl];
    float b = b2[cl];
    for (int t = blockIdx.x; t < NTILES; t += gridDim.x) {
        int n0 = t * 16;
        {
            int rr = tid >> 4, seg = tid & 15;
            *(float4*)&rows[rr][seg * 4] =
                *(const float4*)&aggout[(size_t)(n0 + rr) * 64 + seg * 4];
        }
        __syncthreads();
#pragma unroll
        for (int u = 0; u < 4; ++u) {
            int ln = wid * 4 + u;
            const float4* rp = (const float4*)rows[ln];
            float a0 = 0.f, a1 = 0.f, a2 = 0.f, a3 = 0.f;
#pragma unroll
            for (int jc = 0; jc < HIDDEN / 4; ++jc) {
                float4 r = rp[jc];
                a0 = fmaf(r.x, wcol[jc * 4 + 0], a0);
                a1 = fmaf(r.y, wcol[jc * 4 + 1], a1);
                a2 = fmaf(r.z, wcol[jc * 4 + 2], a2);
                a3 = fmaf(r.w, wcol[jc * 4 + 3], a3);
            }
            float logit = (lane < OUT_CH) ? ((a0 + a1) + (a2 + a3) + b) : -INFINITY;
            float m = logit;
            for (int mask = 32; mask; mask >>= 1) m = fmaxf(m, __shfl_xor(m, mask));
            float ex = (lane < OUT_CH) ? __expf(logit - m) : 0.f;
            float ssum = ex;
            for (int mask = 32; mask; mask >>= 1) ssum += __shfl_xor(ssum, mask);
            if (lane < OUT_CH)
                out[(size_t)(n0 + ln) * OUT_CH + lane] = logit - m - logf(ssum);
        }
        __syncthreads();
    }
}

extern "C" void kernel_launch(void* const* d_in, const int* in_sizes, int n_in,
                              void* d_out, int out_size, void* d_ws, size_t ws_size,
                              hipStream_t stream) {
    const float* x  = (const float*)d_in[0];
    const int*   ei = (const int*)d_in[1];
    // d_in[2] = heads (known 8)
    const float* w1 = (const float*)d_in[3];
    const float* b1 = (const float*)d_in[4];
    const float* wq = (const float*)d_in[5];
    const float* wk = (const float*)d_in[6];
    const float* wv = (const float*)d_in[7];
    const float* w2 = (const float*)d_in[8];
    const float* b2 = (const float*)d_in[9];
    float* out = (float*)d_out;

    char* cur = (char*)d_ws;
    auto alloc = [&](size_t bytes) { char* p = cur; cur += (bytes + 255) & ~(size_t)255; return p; };
    float*         dinv   = (float*)alloc(N_NODES * 4);
    __half*        xh     = (__half*)alloc((size_t)N_NODES * 320 * 2);
    float*         aggout = (float*)alloc((size_t)N_NODES * 64 * 4);
    __half*        qh     = (__half*)alloc((size_t)N_NODES * 64 * 2);
    unsigned char* kvi    = (unsigned char*)alloc((size_t)N_NODES * NUM_LAYERS * 128);
    unsigned char* vh1    = (unsigned char*)alloc((size_t)N_NODES * 64);
    int*           count  = (int*)alloc(N_NODES * 4);
    int*           loc    = (int*)alloc(N_NODES * 4);
    int*           psum   = (int*)alloc(256 * 4);
    int*           rowptr = (int*)alloc((N_NODES + 1) * 4);
    int*           fill   = (int*)alloc(N_NODES * 4);
    int2*          edata  = (int2*)alloc((size_t)E_TOT * 8);

    // CSR build (once)
    k_count_init<<<(N_NODES + 255) / 256, 256, 0, stream>>>(count, fill);
    k_count<<<(N_EDGES + 255) / 256, 256, 0, stream>>>(ei + N_EDGES, count);
    k_scan_a<<<NCHUNK, 256, 0, stream>>>(count, loc, psum);
    k_scan_b<<<1, 256, 0, stream>>>(psum);
    k_scan_c<<<(N_NODES + 255) / 256, 256, 0, stream>>>(count, loc, psum, rowptr,
                                                        dinv, edata);
    k_scatter<<<(N_EDGES + 255) / 256, 256, 0, stream>>>(ei, rowptr, fill, dinv, edata);

    k_h_mfma<<<256, 256, 0, stream>>>(x, w1, b1, xh);

    // Layer 1 (L=1): softmax over a single slot == 1; only v matters.
    k_v1_mfma<<<QKV_WPR / 4, 256, 0, stream>>>(xh, wv, vh1);
    k_edge_l1<<<(N_NODES + 3) / 4, 256, 0, stream>>>(rowptr, edata, vh1, xh);

    for (int i = 1; i < NUM_LAYERS; ++i) {
        int L = i + 1;
        int qkvblk = L * (QKV_WPR / 4);
        const float* wqi = wq + i * 4096;
        const float* wki = wk + i * 4096;
        const float* wvi = wv + i * 4096;
        switch (L) {
            case 2:
                k_qkv_mfma<2><<<qkvblk, 256, 0, stream>>>(xh, wqi, wki, wvi, qh, kvi);
                k_edge_csr8<2><<<(N_NODES + 3) / 4, 256, 0, stream>>>(rowptr, edata, kvi, qh, aggout, xh);
                break;
            case 3:
                k_qkv_mfma<3><<<qkvblk, 256, 0, stream>>>(xh, wqi, wki, wvi, qh, kvi);
                k_edge_csr8<3><<<(N_NODES + 3) / 4, 256, 0, stream>>>(rowptr, edata, kvi, qh, aggout, xh);
                break;
            default:
                k_qkv_mfma<4><<<qkvblk, 256, 0, stream>>>(xh, wqi, wki, wvi, qh, kvi);
                k_edge_csr8<4><<<(N_NODES + 3) / 4, 256, 0, stream>>>(rowptr, edata, kvi, qh, aggout, xh);
                break;
        }
    }
    k_final_lds<<<512, 256, 0, stream>>>(aggout, w2, b2, out);
}